// Round 14
// baseline (98.699 us; speedup 1.0000x reference)
//
#include <hip/hip_runtime.h>

#define BB    2048
#define TT    1024
#define TAILN 8
#define NELEM (BB * TT * TAILN)
#define ROWE  (TT * TAILN)            // 8192 elements per b-row
#define NSTEP 16                      // 64-t blocks per wave: exact, no warm-up

typedef float f32x4 __attribute__((ext_vector_type(4)));

// ---------------------------------------------------------------------------
// terminated-dtype detection (bool u8 / int32 / float32), single block, 16KB.
// ---------------------------------------------------------------------------
static __global__ __launch_bounds__(256)
void detect_kernel(const unsigned int* __restrict__ term, int* __restrict__ flag) {
    __shared__ int sflag;
    if (threadIdx.x == 0) sflag = 0;
    __syncthreads();
    int ev = 0;
    #pragma unroll
    for (int j = 0; j < 16; ++j) {
        unsigned w = term[threadIdx.x + 256u * j];
        if (w == 0x3F800000u) ev |= 2;        // float 1.0f
        else if (w > 1u)      ev |= 1;        // packed bool bytes
    }
    if (ev) atomicOr(&sflag, ev);
    __syncthreads();
    if (threadIdx.x == 0) *flag = sflag;
}

// ---------------------------------------------------------------------------
// EXACT single-pass wave-parallel GAE (no warm-up re-reads: read factor 1.0).
// Wave = (b, tail-half th).  Lane l holds t = t0 + l, tails [4*th, 4*th+4).
// Loads/stores: 16 B per lane at stride 32 B (half-dense); the sibling wave
// (other th, same block) consumes the complementary 16 B sectors via L1/L2,
// so every line is fully used.  Plain stores: L2 write-merges the two halves
// (R1/R2/R4: plain scattered stores gave exact WRITE_SIZE; NT on gappy
// patterns amplified +12% in R11).
// Recurrence: suffix scan of affine maps (A,B) over 64 t's per step via a
// 6-stage shfl butterfly (partner lane+s, s=1..32); carry crosses 64-t
// blocks via lane-0 broadcast (lane 0 = lowest t of the block).  16 steps
// cover [0,1024) exactly -> bit-accurate up to fp reassociation.
// ---------------------------------------------------------------------------
template <int MODE>
__device__ __forceinline__ void gae_wave(
    const float* __restrict__ r, const void* __restrict__ term,
    const float* __restrict__ v, const float* __restrict__ nv,
    float* __restrict__ adv, float* __restrict__ ret,
    int b, int th, int lane)
{
    const unsigned eb = (unsigned)b * (unsigned)ROWE;
    const unsigned lo = (unsigned)lane * 8u + (unsigned)th * 4u;  // elem offset in block

    float c0 = 0.0f, c1 = 0.0f, c2 = 0.0f, c3 = 0.0f;   // carry (this wave's 4 tails)

    #pragma unroll 4
    for (int k = 0; k < NSTEP; ++k) {
        const int t0 = TT - 64 * (k + 1);                // 960, 896, ..., 0
        const unsigned base = eb + (unsigned)t0 * 8u;    // block base (elements)
        const unsigned i = base + lo;

        const float4 R4 = *(const float4*)(r  + i);
        const float4 V4 = *(const float4*)(v  + i);
        const float4 N4 = *(const float4*)(nv + i);

        float n0, n1, n2, n3;
        if (MODE == 1) {
            const unsigned tw = *(const unsigned*)((const unsigned char*)term + i);
            n0 = ( tw        & 0xFFu) ? 0.0f : 1.0f;
            n1 = ((tw >>  8) & 0xFFu) ? 0.0f : 1.0f;
            n2 = ((tw >> 16) & 0xFFu) ? 0.0f : 1.0f;
            n3 = ((tw >> 24) & 0xFFu) ? 0.0f : 1.0f;
        } else if (MODE == 2) {
            const uint4 T4 = *(const uint4*)((const unsigned*)term + i);
            n0 = 1.0f - __uint_as_float(T4.x);
            n1 = 1.0f - __uint_as_float(T4.y);
            n2 = 1.0f - __uint_as_float(T4.z);
            n3 = 1.0f - __uint_as_float(T4.w);
        } else {
            const uint4 T4 = *(const uint4*)((const unsigned*)term + i);
            n0 = T4.x ? 0.0f : 1.0f;  n1 = T4.y ? 0.0f : 1.0f;
            n2 = T4.z ? 0.0f : 1.0f;  n3 = T4.w ? 0.0f : 1.0f;
        }

        // per-t affine maps: gae_t = B + A * gae_{t+1}
        float A0 = 0.9405f * n0, B0 = fmaf(0.99f * n0, N4.x, R4.x) - V4.x;
        float A1 = 0.9405f * n1, B1 = fmaf(0.99f * n1, N4.y, R4.y) - V4.y;
        float A2 = 0.9405f * n2, B2 = fmaf(0.99f * n2, N4.z, R4.z) - V4.z;
        float A3 = 0.9405f * n3, B3 = fmaf(0.99f * n3, N4.w, R4.w) - V4.w;

        #pragma unroll
        for (int s = 1; s < 64; s <<= 1) {               // inclusive suffix over lanes
            const int  src   = lane + s;
            const bool valid = (lane + s) < 64;
            float a, bb;
            a = __shfl(A0, src); bb = __shfl(B0, src);
            B0 = fmaf(A0, valid ? bb : 0.0f, B0); A0 *= valid ? a : 1.0f;
            a = __shfl(A1, src); bb = __shfl(B1, src);
            B1 = fmaf(A1, valid ? bb : 0.0f, B1); A1 *= valid ? a : 1.0f;
            a = __shfl(A2, src); bb = __shfl(B2, src);
            B2 = fmaf(A2, valid ? bb : 0.0f, B2); A2 *= valid ? a : 1.0f;
            a = __shfl(A3, src); bb = __shfl(B3, src);
            B3 = fmaf(A3, valid ? bb : 0.0f, B3); A3 *= valid ? a : 1.0f;
        }

        const float g0 = fmaf(A0, c0, B0);
        const float g1 = fmaf(A1, c1, B1);
        const float g2 = fmaf(A2, c2, B2);
        const float g3 = fmaf(A3, c3, B3);

        f32x4 a4; a4[0] = g0;        a4[1] = g1;        a4[2] = g2;        a4[3] = g3;
        f32x4 r4; r4[0] = g0 + V4.x; r4[1] = g1 + V4.y; r4[2] = g2 + V4.z; r4[3] = g3 + V4.w;
        *(f32x4*)(adv + i) = a4;                         // plain: L2 merges halves
        *(f32x4*)(ret + i) = r4;

        // next block's carry = gae at this block's lowest t (lane 0)
        c0 = __shfl(g0, 0); c1 = __shfl(g1, 0);
        c2 = __shfl(g2, 0); c3 = __shfl(g3, 0);
    }
}

__global__ __launch_bounds__(256)
void gae_kernel(const float* __restrict__ r, const void* __restrict__ term,
                const float* __restrict__ v, const float* __restrict__ nv,
                float* __restrict__ adv, float* __restrict__ ret,
                const int* __restrict__ flag)
{
    const int w    = threadIdx.x >> 6;        // 4 waves: 2 b's x 2 tail-halves
    const int lane = threadIdx.x & 63;
    const int b    = blockIdx.x * 2 + (w >> 1);
    const int th   = w & 1;
    const int f = *flag;                      // wave-uniform
    if (f & 1)      gae_wave<1>(r, term, v, nv, adv, ret, b, th, lane);
    else if (f & 2) gae_wave<2>(r, term, v, nv, adv, ret, b, th, lane);
    else            gae_wave<0>(r, term, v, nv, adv, ret, b, th, lane);
}

extern "C" void kernel_launch(void* const* d_in, const int* in_sizes, int n_in,
                              void* d_out, int out_size, void* d_ws, size_t ws_size,
                              hipStream_t stream) {
    const float* reward = (const float*)d_in[0];
    const void*  term   = d_in[1];
    const float* value  = (const float*)d_in[2];
    const float* nextv  = (const float*)d_in[3];
    float* adv  = (float*)d_out;
    float* ret  = adv + NELEM;
    int*   flag = (int*)d_ws;

    hipLaunchKernelGGL(detect_kernel, dim3(1), dim3(256), 0, stream,
                       (const unsigned int*)term, flag);
    // 1024 blocks x 256 thr = 4096 waves = 16/CU; no LDS; exact (no warm-up)
    hipLaunchKernelGGL(gae_kernel, dim3(BB / 2), dim3(256), 0, stream,
                       reward, term, value, nextv, adv, ret, flag);
}

// Round 15
// 76.237 us; speedup vs baseline: 1.2946x; 1.2946x over previous
//
#include <hip/hip_runtime.h>

#define BB    2048
#define TT    1024
#define TAILN 8
#define NELEM (BB * TT * TAILN)
#define ROWE  (TT * TAILN)            // 8192 elements per b-row
#define NSTEP 20                      // 32-t blocks per wave (uniform both chunks)
#define WSK   4                       // first stored block (warm = 4 blocks = 128 t)

typedef float f32x4 __attribute__((ext_vector_type(4)));

// NT + system-scope store: nt sets the non-temporal (no-LRU-allocate) hint,
// sc1 raises scope so L2/LLC treat it as streaming -> outputs stop evicting
// the 208MB input set from the 256MB Infinity Cache between graph replays.
__device__ __forceinline__ void nt_store4(float* p, f32x4 x) {
    asm volatile("global_store_dwordx4 %0, %1, off sc1 nt"
                 :: "v"(p), "v"(x) : "memory");
}

// ---------------------------------------------------------------------------
// Wave-parallel GAE (R13 structure), single kernel:
//  * per-block detect prologue (no serialized 1-block detect launch: removes
//    a ~3-6us launch bubble per replay).  Each block scans 4096 term words
//    starting at word b0*2048 -- in bool mode that is exactly its own two
//    b-rows (free L2 prewarm); ~160 expected nonzero bytes at 1% density.
//    Evidence: float 1.0f word -> bit2; word>1 -> bool bytes; else int32.
//  * wave = (b, chunk of 512 t); lane l holds float4 of tails (l&1)*4..+3 at
//    t = t0+(l>>1): every load/store is one fully-contiguous 1KB transaction.
//  * suffix scan of affine maps (A,B) via 5-step shfl butterfly; carry
//    crosses 32-t blocks via lane-{0,1} broadcast.
//  * chunks c in {0,1}, hi=(c+1)*512+128, 20 blocks, warm k=0..3 unstored;
//    c==1 clamps warm loads to t0=992 (L1-hot) and resets carry at k==WSK.
//    Stored ranges tile [0,1024) exactly; warm decay 0.9405^128 ~ 3.9e-4.
//  * depth-3 named-buffer rotation, no sched fences (R12: fences regress).
// ---------------------------------------------------------------------------
template <int MODE>
__device__ __forceinline__ void gae_wave(
    const float* __restrict__ r, const void* __restrict__ term,
    const float* __restrict__ v, const float* __restrict__ nv,
    float* __restrict__ adv, float* __restrict__ ret,
    int b, int c, int lane)
{
    const int  hi   = (c + 1) * 512 + 128;     // c==1 -> 1152 (warm loads clamped)
    const bool ctop = (c == 1);
    const unsigned eb = (unsigned)b * (unsigned)ROWE;
    const int th = lane & 1;                   // tail half
    const int tq = lane >> 1;                  // t within 32-t block

    float cx = 0.0f, cy = 0.0f, cz = 0.0f, cw = 0.0f;   // carry (4 tails)

    auto load = [&](int k, float4& R4, float4& V4, float4& N4, uint4& T4) {
        int t0 = hi - 32 * (k + 1);
        if (t0 > TT - 32) t0 = TT - 32;        // c==1 warm clamp (t0=992)
        const unsigned i = eb + (unsigned)t0 * 8u + ((unsigned)lane << 2);
        R4 = *(const float4*)(r  + i);
        V4 = *(const float4*)(v  + i);
        N4 = *(const float4*)(nv + i);
        if (MODE == 1)
            T4.x = ((const unsigned*)term)[((eb + (unsigned)t0 * 8u) >> 2)
                                           + (unsigned)lane];
        else
            T4 = *(const uint4*)((const unsigned*)term + i);
    };

    auto step = [&](int kk, const float4& R4, const float4& V4,
                    const float4& N4, const uint4& T4) {
        float n0, n1, n2, n3;
        if (MODE == 1) {
            n0 = ( T4.x        & 0xFFu) ? 0.0f : 1.0f;
            n1 = ((T4.x >>  8) & 0xFFu) ? 0.0f : 1.0f;
            n2 = ((T4.x >> 16) & 0xFFu) ? 0.0f : 1.0f;
            n3 = ((T4.x >> 24) & 0xFFu) ? 0.0f : 1.0f;
        } else if (MODE == 2) {
            n0 = 1.0f - __uint_as_float(T4.x);
            n1 = 1.0f - __uint_as_float(T4.y);
            n2 = 1.0f - __uint_as_float(T4.z);
            n3 = 1.0f - __uint_as_float(T4.w);
        } else {
            n0 = T4.x ? 0.0f : 1.0f;  n1 = T4.y ? 0.0f : 1.0f;
            n2 = T4.z ? 0.0f : 1.0f;  n3 = T4.w ? 0.0f : 1.0f;
        }
        float A0 = 0.9405f * n0, B0 = fmaf(0.99f * n0, N4.x, R4.x) - V4.x;
        float A1 = 0.9405f * n1, B1 = fmaf(0.99f * n1, N4.y, R4.y) - V4.y;
        float A2 = 0.9405f * n2, B2 = fmaf(0.99f * n2, N4.z, R4.z) - V4.z;
        float A3 = 0.9405f * n3, B3 = fmaf(0.99f * n3, N4.w, R4.w) - V4.w;

        #pragma unroll
        for (int s = 1; s < 32; s <<= 1) {     // inclusive suffix over t's
            const int  src   = lane + 2 * s;
            const bool valid = (tq + s) < 32;
            float a, bb;
            a = __shfl(A0, src); bb = __shfl(B0, src);
            B0 = fmaf(A0, valid ? bb : 0.0f, B0); A0 *= valid ? a : 1.0f;
            a = __shfl(A1, src); bb = __shfl(B1, src);
            B1 = fmaf(A1, valid ? bb : 0.0f, B1); A1 *= valid ? a : 1.0f;
            a = __shfl(A2, src); bb = __shfl(B2, src);
            B2 = fmaf(A2, valid ? bb : 0.0f, B2); A2 *= valid ? a : 1.0f;
            a = __shfl(A3, src); bb = __shfl(B3, src);
            B3 = fmaf(A3, valid ? bb : 0.0f, B3); A3 *= valid ? a : 1.0f;
        }

        // c==1: warm blocks computed clamped garbage; true carry at t=1023 is 0
        if (ctop && kk == WSK) { cx = 0.0f; cy = 0.0f; cz = 0.0f; cw = 0.0f; }

        const float g0 = fmaf(A0, cx, B0);
        const float g1 = fmaf(A1, cy, B1);
        const float g2 = fmaf(A2, cz, B2);
        const float g3 = fmaf(A3, cw, B3);

        if (kk >= WSK) {                       // stored block (t0 in [0, TT-32])
            const int t0 = hi - 32 * (kk + 1);
            const unsigned o = eb + (unsigned)t0 * 8u + ((unsigned)lane << 2);
            f32x4 g4; g4[0] = g0;        g4[1] = g1;        g4[2] = g2;        g4[3] = g3;
            f32x4 rr; rr[0] = g0 + V4.x; rr[1] = g1 + V4.y; rr[2] = g2 + V4.z; rr[3] = g3 + V4.w;
            nt_store4(adv + o, g4);
            nt_store4(ret + o, rr);
        }
        cx = __shfl(g0, th); cy = __shfl(g1, th);
        cz = __shfl(g2, th); cw = __shfl(g3, th);
    };

    float4 rA, vA, nA; uint4 tA;
    float4 rB, vB, nB; uint4 tB;
    float4 rC, vC, nC; uint4 tC;
    load(0, rA, vA, nA, tA);
    load(1, rB, vB, nB, tB);
    load(2, rC, vC, nC, tC);

    #pragma unroll
    for (int k = 0; k < NSTEP; ++k) {          // depth-3 rotation, k static
        if (k % 3 == 0) {
            step(k, rA, vA, nA, tA);
            if (k + 3 < NSTEP) load(k + 3, rA, vA, nA, tA);
        } else if (k % 3 == 1) {
            step(k, rB, vB, nB, tB);
            if (k + 3 < NSTEP) load(k + 3, rB, vB, nB, tB);
        } else {
            step(k, rC, vC, nC, tC);
            if (k + 3 < NSTEP) load(k + 3, rC, vC, nC, tC);
        }
    }
}

__global__ __launch_bounds__(256)
void gae_kernel(const float* __restrict__ r, const void* __restrict__ term,
                const float* __restrict__ v, const float* __restrict__ nv,
                float* __restrict__ adv, float* __restrict__ ret)
{
    // ---- per-block terminated-dtype detection (replaces separate launch) ----
    __shared__ int sflag;
    if (threadIdx.x == 0) sflag = 0;
    __syncthreads();
    {
        const unsigned w0 = (unsigned)(blockIdx.x * 2) * 2048u;  // own rows in bool mode
        int ev = 0;
        #pragma unroll
        for (int j = 0; j < 16; ++j) {
            const unsigned w = ((const unsigned*)term)[w0 + threadIdx.x + 256u * j];
            if (w == 0x3F800000u) ev |= 2;     // float 1.0f
            else if (w > 1u)      ev |= 1;     // packed bool bytes
        }
        if (ev) atomicOr(&sflag, ev);
    }
    __syncthreads();
    const int f = sflag;

    const int w    = threadIdx.x >> 6;        // 4 waves: 2 b's x 2 chunks
    const int lane = threadIdx.x & 63;
    const int b    = blockIdx.x * 2 + (w >> 1);
    const int c    = w & 1;
    if (f & 1)      gae_wave<1>(r, term, v, nv, adv, ret, b, c, lane);
    else if (f & 2) gae_wave<2>(r, term, v, nv, adv, ret, b, c, lane);
    else            gae_wave<0>(r, term, v, nv, adv, ret, b, c, lane);
}

extern "C" void kernel_launch(void* const* d_in, const int* in_sizes, int n_in,
                              void* d_out, int out_size, void* d_ws, size_t ws_size,
                              hipStream_t stream) {
    const float* reward = (const float*)d_in[0];
    const void*  term   = d_in[1];
    const float* value  = (const float*)d_in[2];
    const float* nextv  = (const float*)d_in[3];
    float* adv  = (float*)d_out;
    float* ret  = adv + NELEM;

    // single launch: 1024 blocks x 256 thr = 4096 waves = 16/CU; no detect bubble
    hipLaunchKernelGGL(gae_kernel, dim3(BB / 2), dim3(256), 0, stream,
                       reward, term, value, nextv, adv, ret);
}

// Round 17
// 66.916 us; speedup vs baseline: 1.4750x; 1.1393x over previous
//
#include <hip/hip_runtime.h>

#define BB    2048
#define TT    1024
#define TAILN 8
#define NELEM (BB * TT * TAILN)
#define ROWE  (TT * TAILN)            // 8192 elements per b-row
#define NSTEP 32                      // 32-t blocks per wave: exact, no warm-up

typedef float f32x4 __attribute__((ext_vector_type(4)));

// ---------------------------------------------------------------------------
// EXACT single-pass wave-parallel GAE, single fused kernel, read factor 1.0.
// Rebuilt from individually-proven components only:
//  * dense layout + suffix-scan step: R13/R15 (lane l = float4 of tails
//    (l&1)*4..+3 at t = t0+(l>>1); i = eb + t0*8 + 4*lane -> 1KB/instr).
//  * control flow: R14's simple load->compute->store loop, unroll 4 (no
//    named-buffer rotation, no inline-asm stores -- R16's unproven combo).
//  * stores: __builtin_nontemporal_store on dense full lines (R10/R13:
//    exact 131072KB WRITE_SIZE, correct across many rounds).
//  * fused per-block dtype detect (R15): 2048 words (8KB) at the block's
//    own rows (bool mode).  Bool evidence (word>1): ~60 expected hits,
//    P(miss) ~ e^-62.  Float evidence 0x3F800000: ~20 hits; a missed float
//    detection is harmless (int32-nd == float-nd for exact 0/1 data).
//  * suffix scan of affine maps (A,B) via 5-step shfl butterfly; carry
//    crosses 32-t blocks via lane-{0,1} broadcast; 32 steps tile [0,1024).
// ---------------------------------------------------------------------------
template <int MODE>
__device__ __forceinline__ void gae_wave(
    const float* __restrict__ r, const void* __restrict__ term,
    const float* __restrict__ v, const float* __restrict__ nv,
    float* __restrict__ adv, float* __restrict__ ret,
    int b, int lane)
{
    const unsigned eb = (unsigned)b * (unsigned)ROWE;
    const int th = lane & 1;                   // tail half
    const int tq = lane >> 1;                  // t within 32-t block

    float cx = 0.0f, cy = 0.0f, cz = 0.0f, cw = 0.0f;   // carry (4 tails)

    #pragma unroll 4
    for (int k = 0; k < NSTEP; ++k) {
        const int t0 = TT - 32 * (k + 1);                // 992, 960, ..., 0
        const unsigned i = eb + (unsigned)t0 * 8u + ((unsigned)lane << 2);

        const float4 R4 = *(const float4*)(r  + i);
        const float4 V4 = *(const float4*)(v  + i);
        const float4 N4 = *(const float4*)(nv + i);

        float n0, n1, n2, n3;
        if (MODE == 1) {
            const unsigned tw =
                ((const unsigned*)term)[((eb + (unsigned)t0 * 8u) >> 2) + (unsigned)lane];
            n0 = ( tw        & 0xFFu) ? 0.0f : 1.0f;
            n1 = ((tw >>  8) & 0xFFu) ? 0.0f : 1.0f;
            n2 = ((tw >> 16) & 0xFFu) ? 0.0f : 1.0f;
            n3 = ((tw >> 24) & 0xFFu) ? 0.0f : 1.0f;
        } else if (MODE == 2) {
            const uint4 T4 = *(const uint4*)((const unsigned*)term + i);
            n0 = 1.0f - __uint_as_float(T4.x);
            n1 = 1.0f - __uint_as_float(T4.y);
            n2 = 1.0f - __uint_as_float(T4.z);
            n3 = 1.0f - __uint_as_float(T4.w);
        } else {
            const uint4 T4 = *(const uint4*)((const unsigned*)term + i);
            n0 = T4.x ? 0.0f : 1.0f;  n1 = T4.y ? 0.0f : 1.0f;
            n2 = T4.z ? 0.0f : 1.0f;  n3 = T4.w ? 0.0f : 1.0f;
        }

        // per-t affine maps: gae_t = B + A * gae_{t+1}
        float A0 = 0.9405f * n0, B0 = fmaf(0.99f * n0, N4.x, R4.x) - V4.x;
        float A1 = 0.9405f * n1, B1 = fmaf(0.99f * n1, N4.y, R4.y) - V4.y;
        float A2 = 0.9405f * n2, B2 = fmaf(0.99f * n2, N4.z, R4.z) - V4.z;
        float A3 = 0.9405f * n3, B3 = fmaf(0.99f * n3, N4.w, R4.w) - V4.w;

        #pragma unroll
        for (int s = 1; s < 32; s <<= 1) {     // inclusive suffix over t's
            const int  src   = lane + 2 * s;
            const bool valid = (tq + s) < 32;
            float a, bb;
            a = __shfl(A0, src); bb = __shfl(B0, src);
            B0 = fmaf(A0, valid ? bb : 0.0f, B0); A0 *= valid ? a : 1.0f;
            a = __shfl(A1, src); bb = __shfl(B1, src);
            B1 = fmaf(A1, valid ? bb : 0.0f, B1); A1 *= valid ? a : 1.0f;
            a = __shfl(A2, src); bb = __shfl(B2, src);
            B2 = fmaf(A2, valid ? bb : 0.0f, B2); A2 *= valid ? a : 1.0f;
            a = __shfl(A3, src); bb = __shfl(B3, src);
            B3 = fmaf(A3, valid ? bb : 0.0f, B3); A3 *= valid ? a : 1.0f;
        }

        const float g0 = fmaf(A0, cx, B0);
        const float g1 = fmaf(A1, cy, B1);
        const float g2 = fmaf(A2, cz, B2);
        const float g3 = fmaf(A3, cw, B3);

        f32x4 g4; g4[0] = g0;        g4[1] = g1;        g4[2] = g2;        g4[3] = g3;
        f32x4 rr; rr[0] = g0 + V4.x; rr[1] = g1 + V4.y; rr[2] = g2 + V4.z; rr[3] = g3 + V4.w;
        __builtin_nontemporal_store(g4, (f32x4*)(adv + i));
        __builtin_nontemporal_store(rr, (f32x4*)(ret + i));

        // next block's carry = gae at this block's lowest t (lanes 0/1)
        cx = __shfl(g0, th); cy = __shfl(g1, th);
        cz = __shfl(g2, th); cw = __shfl(g3, th);
    }
}

__global__ __launch_bounds__(256)
void gae_kernel(const float* __restrict__ r, const void* __restrict__ term,
                const float* __restrict__ v, const float* __restrict__ nv,
                float* __restrict__ adv, float* __restrict__ ret)
{
    // ---- per-block terminated-dtype detection (2048 words = 8KB) ----
    __shared__ int sflag;
    if (threadIdx.x == 0) sflag = 0;
    __syncthreads();
    {
        const unsigned w0 = (unsigned)blockIdx.x * 8192u;  // own rows in bool mode
        int ev = 0;
        #pragma unroll
        for (int j = 0; j < 8; ++j) {
            const unsigned w = ((const unsigned*)term)[w0 + threadIdx.x + 256u * j];
            if (w == 0x3F800000u) ev |= 2;     // float 1.0f
            else if (w > 1u)      ev |= 1;     // packed bool bytes
        }
        if (ev) atomicOr(&sflag, ev);
    }
    __syncthreads();
    const int f = sflag;

    const int w    = threadIdx.x >> 6;        // 4 waves = 4 b-rows per block
    const int lane = threadIdx.x & 63;
    const int b    = blockIdx.x * 4 + w;
    if (f & 1)      gae_wave<1>(r, term, v, nv, adv, ret, b, lane);
    else if (f & 2) gae_wave<2>(r, term, v, nv, adv, ret, b, lane);
    else            gae_wave<0>(r, term, v, nv, adv, ret, b, lane);
}

extern "C" void kernel_launch(void* const* d_in, const int* in_sizes, int n_in,
                              void* d_out, int out_size, void* d_ws, size_t ws_size,
                              hipStream_t stream) {
    const float* reward = (const float*)d_in[0];
    const void*  term   = d_in[1];
    const float* value  = (const float*)d_in[2];
    const float* nextv  = (const float*)d_in[3];
    float* adv  = (float*)d_out;
    float* ret  = adv + NELEM;

    // single launch: 512 blocks x 256 thr = 2048 waves = 8/CU; exact scan
    hipLaunchKernelGGL(gae_kernel, dim3(BB / 4), dim3(256), 0, stream,
                       reward, term, value, nextv, adv, ret);
}